// Round 7
// baseline (83.908 us; speedup 1.0000x reference)
//
#include <hip/hip_runtime.h>

// Problem constants
#define FDIM 256
#define BDIM 32
#define MDIM 32768
#define NB   512        // m-tiles (64 m each); one partial per (b, tile)

// ws layout (float units)
#define WS_EM    0                       // (unused after fusion; kept for layout stability)
#define WS_EX    (WS_EM + MDIM*FDIM)
#define WS_W2N   (WS_EX + BDIM*FDIM)
#define WS_PMAX  (WS_W2N + FDIM)
#define WS_PSUM  (WS_PMAX + BDIM*NB)
#define WS_PARG  (WS_PSUM + BDIM*NB)
#define WS_WIN   (WS_PARG + BDIM*NB)
#define WS_BEST  (WS_WIN + 32)
#define WS_GMAX  (WS_BEST + 32)
#define WS_GSUM  (WS_GMAX + 32)
#define WS_GARG  (WS_GSUM + 32)
#define WS_WH    (WS_GARG + 32)          // W1m hi: 65536 bf16
#define WS_WL    (WS_WH + 32768)         // W1m lo

#define C2 2.8853900817779268f   // 2*log2(e): e^{2x} = 2^(C2*x)

typedef __attribute__((ext_vector_type(8))) short bf16x8;
typedef __attribute__((ext_vector_type(8))) unsigned short ushort8;
typedef __attribute__((ext_vector_type(4))) unsigned short ushort4v;
typedef __attribute__((ext_vector_type(4))) float f32x4;

__device__ inline unsigned short f2bf(float x) {      // RNE f32 -> bf16
  unsigned u = __float_as_uint(x);
  return (unsigned short)((u + 0x7fffu + ((u >> 16) & 1u)) >> 16);
}
__device__ inline float bf2f(unsigned short h) {
  return __uint_as_float(((unsigned)h) << 16);
}

// K1: blocks 0..31: Ex[b][f] = 2^(C2*(b1[f] + sum_k input[b][k]*W1[f*512+k])); w2n = -2*W2
//     blocks 32..95: split W1m into bf16 hi/lo arrays
__global__ __launch_bounds__(256) void k1_prep(const float* __restrict__ input,
                                               const float* __restrict__ W1,
                                               const float* __restrict__ b1,
                                               const float* __restrict__ W2,
                                               float* __restrict__ Ex,
                                               float* __restrict__ w2n,
                                               unsigned short* __restrict__ wh,
                                               unsigned short* __restrict__ wl) {
  if (blockIdx.x < BDIM) {
    const int b = blockIdx.x, f = threadIdx.x;
    const float* in = input + b * FDIM;
    const float* w  = W1 + (size_t)f * 512;
    float acc = b1[f];
    #pragma unroll 8
    for (int k = 0; k < FDIM; k += 4) {
      float4 iv = *(const float4*)(in + k);
      float4 wv = *(const float4*)(w + k);
      acc = fmaf(iv.x, wv.x, acc); acc = fmaf(iv.y, wv.y, acc);
      acc = fmaf(iv.z, wv.z, acc); acc = fmaf(iv.w, wv.w, acc);
    }
    Ex[b * FDIM + f] = __builtin_amdgcn_exp2f(acc * C2);
    if (b == 0) w2n[f] = -2.0f * W2[f];
  } else {
    int id = ((blockIdx.x - BDIM) * 256 + threadIdx.x) * 4;   // 0..65532
    int f = id >> 8, c = id & 255;
    float4 v = *(const float4*)(W1 + (size_t)f * 512 + 256 + c);
    float xs[4] = {v.x, v.y, v.z, v.w};
    #pragma unroll
    for (int e = 0; e < 4; ++e) {
      unsigned short h = f2bf(xs[e]);
      wh[id + e] = h;
      wl[id + e] = f2bf(xs[e] - bf2f(h));
    }
  }
}

// K23: fused k2_mfma + k3_score + out-copy. DOUBLE-BUFFERED staging, ONE
// __syncthreads per k-step (vs 2 in R2..R6): per window, STAGE(s+1)->buf[nxt]
// is issued BEFORE frags+MFMA(s) from buf[cur], so global loads / L2 loads /
// ds_writes / ds_reads / MFMA all co-issue inside one window across the 16
// waves. WAR-safe: buf[nxt] was last frag-read two windows ago (one barrier
// between). Buffers selected by compile-time literals (2x unrolled ping/pong)
// -> no runtime indexing, no spill-prone reg prefetch, no raw barriers.
// LDS = 2 x 51200 = 102400 B -> 1 block/CU (R5/R6 proved wave-count invariance,
// so losing the 2nd co-resident block is free).
// Phase 2 (unchanged): two f-halves, emT [128][68] aliased over buf0.
__global__ __launch_bounds__(1024, 4) void k23_fused(const float* __restrict__ mem,
                                                     const unsigned short* __restrict__ wh,
                                                     const unsigned short* __restrict__ wl,
                                                     const float* __restrict__ Ex,
                                                     const float* __restrict__ w2n,
                                                     float* __restrict__ pmax,
                                                     float* __restrict__ psum,
                                                     int* __restrict__ parg,
                                                     float* __restrict__ out) {
  __shared__ __align__(16) char smem[102400];    // 2 x (AH 5120|AL 5120|BH 20480|BL 20480)
  unsigned short* AHp[2] = {(unsigned short*)(smem),         (unsigned short*)(smem + 51200)};
  unsigned short* ALp[2] = {(unsigned short*)(smem + 5120),  (unsigned short*)(smem + 56320)};
  unsigned short* BHp[2] = {(unsigned short*)(smem + 10240), (unsigned short*)(smem + 61440)};
  unsigned short* BLp[2] = {(unsigned short*)(smem + 30720), (unsigned short*)(smem + 81920)};
  float* emT = (float*)smem;                     // phase 2: [128][68] f32 (34816 B, over buf0)

  const int tid = threadIdx.x;
  const int lane = tid & 63, wid = tid >> 6;     // wid 0..15
  const int m0 = blockIdx.x * 64;
  const int rb = lane & 15, g8 = (lane >> 4) * 8;
  const int mh = wid & 3;        // m-16-subtile (16 rows)
  const int fq = wid >> 2;       // f-quarter (64 cols)

  f32x4 acc[4];
  #pragma unroll
  for (int j = 0; j < 4; ++j) acc[j] = (f32x4){0.f, 0.f, 0.f, 0.f};

  // stage k-step s into buffer `buf` (A: 512 thr x 4 elems; B: 512 thr x 2 uint4 pairs)
  auto STAGE = [&](int s, int buf) {
    const int k0 = s * 32;
    if (tid < 512) {   // A: 64 rows x 32 k, split hi/lo; folded out=mem store
      int r = tid >> 3, c4 = (tid & 7) * 4;
      const float* mrow = mem + (size_t)(m0 + r) * 256 + k0 + c4;
      float4 a0 = *(const float4*)(mrow);
      *(float4*)(out + (size_t)(m0 + r) * 256 + k0 + c4) = a0;
      float xs[4] = {a0.x, a0.y, a0.z, a0.w};
      ushort4v ahv, alv;
      #pragma unroll
      for (int e = 0; e < 4; ++e) {
        unsigned short h = f2bf(xs[e]);
        ahv[e] = h;
        alv[e] = f2bf(xs[e] - bf2f(h));
      }
      *(ushort4v*)&AHp[buf][r * 40 + c4] = ahv;
      *(ushort4v*)&ALp[buf][r * 40 + c4] = alv;
    } else {           // B: 256 rows x 32 k (pre-split, L2-resident)
      int t2 = tid - 512;
      #pragma unroll
      for (int q = 0; q < 2; ++q) {
        int id = q * 512 + t2, br = id >> 2, bc = (id & 3) * 8;
        *(uint4*)&BHp[buf][br * 40 + bc] = *(const uint4*)(wh + (size_t)br * 256 + k0 + bc);
        *(uint4*)&BLp[buf][br * 40 + bc] = *(const uint4*)(wl + (size_t)br * 256 + k0 + bc);
      }
    }
  };

  // frag reads + 12 MFMA from buffer `buf`
  auto COMPUTE = [&](int buf) {
    bf16x8 fah, fal, fbh[4], fbl[4];
    fah = *(const bf16x8*)&AHp[buf][(mh * 16 + rb) * 40 + g8];
    fal = *(const bf16x8*)&ALp[buf][(mh * 16 + rb) * 40 + g8];
    #pragma unroll
    for (int j = 0; j < 4; ++j) {
      fbh[j] = *(const bf16x8*)&BHp[buf][(fq * 64 + j * 16 + rb) * 40 + g8];
      fbl[j] = *(const bf16x8*)&BLp[buf][(fq * 64 + j * 16 + rb) * 40 + g8];
    }
    #pragma unroll
    for (int j = 0; j < 4; ++j) {
      acc[j] = __builtin_amdgcn_mfma_f32_16x16x32_bf16(fah, fbh[j], acc[j], 0, 0, 0);
      acc[j] = __builtin_amdgcn_mfma_f32_16x16x32_bf16(fah, fbl[j], acc[j], 0, 0, 0);
      acc[j] = __builtin_amdgcn_mfma_f32_16x16x32_bf16(fal, fbh[j], acc[j], 0, 0, 0);
    }
  };

  STAGE(0, 0);                     // prologue
  #pragma unroll
  for (int s2 = 0; s2 < 8; s2 += 2) {
    __syncthreads();               // buf0 staged/visible; buf1 frag-reads (s2-1) retired
    if (s2 < 7) STAGE(s2 + 1, 1);  // issue loads early; writes overlap MFMA below
    COMPUTE(0);
    __syncthreads();               // buf1 staged/visible; buf0 frag-reads (s2) retired
    if (s2 + 2 < 8) STAGE(s2 + 2, 0);
    COMPUTE(1);
  }

  // Epilogue + phase 2 in TWO f-halves (emT [128][68] aliased over buf0).
  // Pass h: waves with fq in {2h,2h+1} (wid>>3 == h) write their 128-f slab;
  // then ALL 16 waves score f in [128h, 128h+128), each wave owns 2 b.
  // D frag: f = fq*64 + j*16 + rb; m_local = mh*16 + (lane>>4)*4 + r.
  const int wuid = __builtin_amdgcn_readfirstlane(wid);  // 0..15
  const float* ex0 = Ex + (size_t)(wuid * 2 + 0) * FDIM;
  const float* ex1 = Ex + (size_t)(wuid * 2 + 1) * FDIM;
  float acc0 = 0.f, acc1 = 0.f;

  #pragma unroll
  for (int h = 0; h < 2; ++h) {
    __syncthreads();   // h=0: all frag reads done; h=1: pass-0 emT reads done
    if ((wid >> 3) == h) {
      #pragma unroll
      for (int j = 0; j < 4; ++j) {
        const int fl = (fq * 64 + j * 16 + rb) - h * 128;   // 0..127 local
        const int mloc = mh * 16 + (lane >> 4) * 4;
        float4 v;
        v.x = __builtin_amdgcn_exp2f(acc[j][0] * C2);
        v.y = __builtin_amdgcn_exp2f(acc[j][1] * C2);
        v.z = __builtin_amdgcn_exp2f(acc[j][2] * C2);
        v.w = __builtin_amdgcn_exp2f(acc[j][3] * C2);
        *(float4*)(emT + fl * 68 + mloc) = v;
      }
    }
    __syncthreads();

    // score this 128-f slab: 4-f groups share one rcp per b:
    //   sum_i w_i/u_i = [(w0u1+w1u0)u2u3 + (w2u3+w3u2)u0u1] / (u0u1u2u3)
    #pragma unroll 2
    for (int fl2 = 0; fl2 < 128; fl2 += 4) {
      const int fg = h * 128 + fl2;
      float e0 = emT[(fl2 + 0) * 68 + lane];
      float e1 = emT[(fl2 + 1) * 68 + lane];
      float e2 = emT[(fl2 + 2) * 68 + lane];
      float e3 = emT[(fl2 + 3) * 68 + lane];
      float w0 = w2n[fg + 0], w1 = w2n[fg + 1];   // uniform -> SGPR
      float w2 = w2n[fg + 2], w3 = w2n[fg + 3];
      #define SCORE4(exP, accV)                                          \
      {                                                                  \
        float u0 = fmaf(e0, exP[fg + 0], 1.f);                           \
        float u1 = fmaf(e1, exP[fg + 1], 1.f);                           \
        float u2 = fmaf(e2, exP[fg + 2], 1.f);                           \
        float u3 = fmaf(e3, exP[fg + 3], 1.f);                           \
        float p01 = u0 * u1, p23 = u2 * u3;                              \
        float den = p01 * p23;                                           \
        float t0 = fmaf(w1, u0, w0 * u1);                                \
        float t1 = fmaf(w3, u2, w2 * u3);                                \
        float num = fmaf(t1, p01, t0 * p23);                             \
        accV = fmaf(num, __builtin_amdgcn_rcpf(den), accV);              \
      }
      SCORE4(ex0, acc0)
      SCORE4(ex1, acc1)
      #undef SCORE4
    }
  }

  // wave reduce per owned b: max+argmax over 64 m lanes, then sumexp
  float accb[2] = {acc0, acc1};
  const int blk = blockIdx.x;
  #pragma unroll
  for (int bi = 0; bi < 2; ++bi) {
    float s = accb[bi]; int idx = m0 + lane;
    #pragma unroll
    for (int off = 32; off > 0; off >>= 1) {
      float so = __shfl_xor(s, off);
      int   io = __shfl_xor(idx, off);
      if (so > s || (so == s && io < idx)) { s = so; idx = io; }
    }
    float ex = __expf(accb[bi] - s);
    #pragma unroll
    for (int off = 32; off > 0; off >>= 1) ex += __shfl_xor(ex, off);
    if (lane == 0) {
      int b = wuid * 2 + bi;
      pmax[b * NB + blk] = s;
      psum[b * NB + blk] = ex;
      parg[b * NB + blk] = idx;
    }
  }
}

// K45: fused reduce + select + patch (single block, 16 waves).
// Wave w merges the 512 partials for b = 2w and 2w+1 (8 per lane + shfl
// tree), results in LDS; then dedup (winner = LARGEST masked b per slot);
// then patch winning rows out[ga[b]] = input[b] (32 threads per b).
__global__ __launch_bounds__(1024) void k45_finish(const float* __restrict__ pmax,
                                                   const float* __restrict__ psum,
                                                   const int* __restrict__ parg,
                                                   const float* __restrict__ thr_p,
                                                   const float* __restrict__ input,
                                                   float* __restrict__ out) {
  __shared__ float gm[BDIM], gs[BDIM];
  __shared__ int   ga[BDIM], wn[BDIM];
  const int tid = threadIdx.x, lane = tid & 63, w = tid >> 6;   // 16 waves
  #pragma unroll
  for (int half = 0; half < 2; ++half) {
    const int b = w * 2 + half;
    float cm = -3.0e38f, cs = 0.f; int ca = 0x7fffffff;
    #pragma unroll
    for (int t = 0; t < NB / 64; ++t) {
      int i = t * 64 + lane;
      float s = pmax[b * NB + i];
      float p = psum[b * NB + i];
      int   a = parg[b * NB + i];
      if (s > cm)      { cs = cs * __expf(cm - s) + p; cm = s; ca = a; }
      else if (s == cm){ cs += p; if (a < ca) ca = a; }
      else             { cs += p * __expf(s - cm); }
    }
    #pragma unroll
    for (int off = 32; off > 0; off >>= 1) {
      float om = __shfl_xor(cm, off);
      float os = __shfl_xor(cs, off);
      int   oa = __shfl_xor(ca, off);
      if (om > cm)      { cs = cs * __expf(cm - om) + os; cm = om; ca = oa; }
      else if (om == cm){ cs += os; if (oa < ca) ca = oa; }
      else              { cs += os * __expf(om - cm); }
    }
    if (lane == 0) { gm[b] = cm; gs[b] = cs; ga[b] = ca; }
  }
  __syncthreads();
  if (tid < BDIM) {
    const float thr = *thr_p;
    const int me = ga[tid];
    int w_ = (1.0f / gs[tid] > thr) ? 1 : 0;   // maxw = 1/sumexp
    if (w_) {
      for (int b2 = tid + 1; b2 < BDIM; ++b2)
        if ((1.0f / gs[b2] > thr) && ga[b2] == me) { w_ = 0; break; }
    }
    wn[tid] = w_;
  }
  __syncthreads();
  {
    const int b = tid >> 5, sub = tid & 31;
    if (wn[b]) {
      const int m = ga[b];
      *(float4*)(out + (size_t)m * 256 + sub * 8) =
          *(const float4*)(input + (size_t)b * 256 + sub * 8);
      *(float4*)(out + (size_t)m * 256 + sub * 8 + 4) =
          *(const float4*)(input + (size_t)b * 256 + sub * 8 + 4);
    }
  }
}

extern "C" void kernel_launch(void* const* d_in, const int* in_sizes, int n_in,
                              void* d_out, int out_size, void* d_ws, size_t ws_size,
                              hipStream_t stream) {
  const float* input  = (const float*)d_in[0];
  const float* memory = (const float*)d_in[1];
  const float* W1     = (const float*)d_in[2];
  const float* b1     = (const float*)d_in[3];
  const float* W2     = (const float*)d_in[4];
  // d_in[5] = b2: constant score shift, softmax/argmax/maxw invariant -> unused
  const float* thr    = (const float*)d_in[6];

  float* ws   = (float*)d_ws;
  float* Ex   = ws + WS_EX;
  float* w2n  = ws + WS_W2N;
  float* pmax = ws + WS_PMAX;
  float* psum = ws + WS_PSUM;
  int*   parg = (int*)(ws + WS_PARG);
  unsigned short* wh = (unsigned short*)(ws + WS_WH);
  unsigned short* wl = (unsigned short*)(ws + WS_WL);
  float* out  = (float*)d_out;

  hipLaunchKernelGGL(k1_prep,    dim3(BDIM + 64), dim3(256),  0, stream, input, W1, b1, W2, Ex, w2n, wh, wl);
  hipLaunchKernelGGL(k23_fused,  dim3(MDIM / 64), dim3(1024), 0, stream, memory, wh, wl, Ex, w2n, pmax, psum, parg, out);
  hipLaunchKernelGGL(k45_finish, dim3(1),         dim3(1024), 0, stream, pmax, psum, parg, thr, input, out);
}